// Round 1
// baseline (263.629 us; speedup 1.0000x reference)
//
#include <hip/hip_runtime.h>
#include <hip/hip_bf16.h>
#include <math.h>

typedef __attribute__((ext_vector_type(8))) short bf16x8;
typedef __attribute__((ext_vector_type(4))) float f32x4;

__device__ inline short f2bf(float f) {
    union { float f; unsigned u; } x; x.f = f;
    unsigned r = (x.u + 0x7FFFu + ((x.u >> 16) & 1u)) >> 16;
    return (short)r;
}

// ---------------------------------------------------------------------------
// Kernel 1: qkv = array(4096x256) @ Wqkv(256x3072), output split to
// Q/K/V bf16 buffers in (B,H,N,64) layout.
// Block tile 64(M) x 64(N), 4 waves, wave w does rows [16w,16w+16).
// ---------------------------------------------------------------------------
__global__ __launch_bounds__(256) void qkv_kernel(
        const float* __restrict__ A, const float* __restrict__ W,
        short* __restrict__ Qb, short* __restrict__ Kb, short* __restrict__ Vb) {
    __shared__ short As[64 * 40];   // rows padded 32->40 elems (80B, 16B-mult)
    __shared__ short Bs[64 * 40];   // transposed: Bs[n][k]
    int m0 = blockIdx.x * 64;
    int n0 = blockIdx.y * 64;
    int t = threadIdx.x;
    int wave = t >> 6, lane = t & 63;
    int quad = lane >> 4, l16 = lane & 15;
    f32x4 acc[4] = {};
    for (int k0 = 0; k0 < 256; k0 += 32) {
        __syncthreads();
        {   // stage A tile 64x32 (fp32 -> bf16)
            int i = t * 8;
            int row = i >> 5, col = i & 31;
            const float* src = A + (m0 + row) * 256 + k0 + col;
            short* dst = &As[row * 40 + col];
#pragma unroll
            for (int j = 0; j < 8; ++j) dst[j] = f2bf(src[j]);
        }
        {   // stage B tile 32x64 transposed: Bs[n][k]
            int i = t * 8;
            int kr = i >> 6, col = i & 63;
            const float* src = W + (k0 + kr) * 3072 + n0 + col;
#pragma unroll
            for (int j = 0; j < 8; ++j) Bs[(col + j) * 40 + kr] = f2bf(src[j]);
        }
        __syncthreads();
        bf16x8 af = *(const bf16x8*)&As[(wave * 16 + l16) * 40 + quad * 8];
#pragma unroll
        for (int c = 0; c < 4; ++c) {
            bf16x8 bfr = *(const bf16x8*)&Bs[(c * 16 + l16) * 40 + quad * 8];
            acc[c] = __builtin_amdgcn_mfma_f32_16x16x32_bf16(af, bfr, acc[c], 0, 0, 0);
        }
    }
    // C/D layout: col = lane&15, row = quad*4 + r
#pragma unroll
    for (int c = 0; c < 4; ++c) {
#pragma unroll
        for (int r = 0; r < 4; ++r) {
            int gm = m0 + wave * 16 + quad * 4 + r;   // 0..4095
            int gc = n0 + c * 16 + l16;               // 0..3071
            int b = gm >> 11, n = gm & 2047;
            int sel = gc >> 10, within = gc & 1023;
            int h = within >> 6, dim = within & 63;
            short* dst = (sel == 0) ? Qb : ((sel == 1) ? Kb : Vb);
            dst[(((b * 16 + h) * 2048 + n) << 6) + dim] = f2bf(acc[c][r]);
        }
    }
}

// ---------------------------------------------------------------------------
// Kernel 2: flash attention. grid = (32 q-tiles, 32 bh). 4 waves/block,
// wave w owns Q rows [qt*64 + 16w, +16). Key tiles of 64.
// ---------------------------------------------------------------------------
__global__ __launch_bounds__(256) void attn_kernel(
        const short* __restrict__ Qb, const short* __restrict__ Kb,
        const short* __restrict__ Vb, short* __restrict__ AO) {
    __shared__ short VT[64 * 80];       // V transposed: VT[dim][key]
    __shared__ short Pl[4][16 * 80];    // per-wave P, rows padded to 80
    int bh = blockIdx.y;                // 0..31
    int qt = blockIdx.x;                // 0..31
    int b = bh >> 4, h = bh & 15;
    int t = threadIdx.x, wave = t >> 6, lane = t & 63;
    int quad = lane >> 4, l16 = lane & 15;
    const short* Qp = Qb + (size_t)bh * 2048 * 64;
    const short* Kp = Kb + (size_t)bh * 2048 * 64;
    const short* Vp = Vb + (size_t)bh * 2048 * 64;
    int q0 = qt * 64 + wave * 16;
    // Q fragments (A-layout: m=lane&15, k=quad*8+j), kept in regs all kernel
    bf16x8 qf0 = *(const bf16x8*)&Qp[(q0 + l16) * 64 + quad * 8];
    bf16x8 qf1 = *(const bf16x8*)&Qp[(q0 + l16) * 64 + 32 + quad * 8];
    f32x4 o[4] = {};
    float m_run[4], l_run[4];
#pragma unroll
    for (int r = 0; r < 4; ++r) { m_run[r] = -1e30f; l_run[r] = 0.f; }

    for (int kt = 0; kt < 32; ++kt) {
        __syncthreads();
        {   // stage V tile (64 keys x 64 dims) transposed into VT[dim][key]
            int key = t >> 2;
            int d0 = (t & 3) * 16;
            const short* src = Vp + ((kt * 64 + key) << 6) + d0;
#pragma unroll
            for (int j = 0; j < 16; ++j) VT[(d0 + j) * 80 + key] = src[j];
        }
        __syncthreads();
        // S = Q K^T for 4 key sub-tiles of 16
        f32x4 s[4];
#pragma unroll
        for (int c = 0; c < 4; ++c) {
            int key = ((kt * 64 + c * 16 + l16) << 6);
            bf16x8 kf0 = *(const bf16x8*)&Kp[key + quad * 8];
            bf16x8 kf1 = *(const bf16x8*)&Kp[key + 32 + quad * 8];
            f32x4 z = {};
            z = __builtin_amdgcn_mfma_f32_16x16x32_bf16(qf0, kf0, z, 0, 0, 0);
            z = __builtin_amdgcn_mfma_f32_16x16x32_bf16(qf1, kf1, z, 0, 0, 0);
            s[c] = z * 0.125f;   // 1/sqrt(64)
        }
        // online softmax: rows = quad*4+r, cols spread over 16 lanes (l16)
        float mx[4], alpha[4], sum[4];
#pragma unroll
        for (int r = 0; r < 4; ++r) {
            float v = fmaxf(fmaxf(s[0][r], s[1][r]), fmaxf(s[2][r], s[3][r]));
#pragma unroll
            for (int off = 1; off < 16; off <<= 1)
                v = fmaxf(v, __shfl_xor(v, off, 64));
            float mn = fmaxf(m_run[r], v);
            alpha[r] = __expf(m_run[r] - mn);
            m_run[r] = mn;
            mx[r] = mn;
            sum[r] = 0.f;
        }
        short* Pw = &Pl[wave][0];
#pragma unroll
        for (int c = 0; c < 4; ++c) {
#pragma unroll
            for (int r = 0; r < 4; ++r) {
                float p = __expf(s[c][r] - mx[r]);
                sum[r] += p;
                Pw[(quad * 4 + r) * 80 + c * 16 + l16] = f2bf(p);
            }
        }
#pragma unroll
        for (int r = 0; r < 4; ++r) {
#pragma unroll
            for (int off = 1; off < 16; off <<= 1)
                sum[r] += __shfl_xor(sum[r], off, 64);
            l_run[r] = l_run[r] * alpha[r] + sum[r];
        }
#pragma unroll
        for (int dt = 0; dt < 4; ++dt)
#pragma unroll
            for (int r = 0; r < 4; ++r) o[dt][r] *= alpha[r];
        __syncthreads();   // P writes visible before A-layout re-read
        // O += P(16x64) @ V(64x64)
#pragma unroll
        for (int c = 0; c < 2; ++c) {
            bf16x8 pf = *(const bf16x8*)&Pw[l16 * 80 + c * 32 + quad * 8];
#pragma unroll
            for (int dt = 0; dt < 4; ++dt) {
                bf16x8 vf = *(const bf16x8*)&VT[(dt * 16 + l16) * 80 + c * 32 + quad * 8];
                o[dt] = __builtin_amdgcn_mfma_f32_16x16x32_bf16(pf, vf, o[dt], 0, 0, 0);
            }
        }
    }
    // epilogue: divide by l, write AO[b][n][h*64+dim] (4096 x 1024 bf16)
#pragma unroll
    for (int dt = 0; dt < 4; ++dt) {
#pragma unroll
        for (int r = 0; r < 4; ++r) {
            float val = o[dt][r] / l_run[r];
            int qrow = q0 + quad * 4 + r;
            AO[((size_t)(b * 2048 + qrow) << 10) + h * 64 + dt * 16 + l16] = f2bf(val);
        }
    }
}

// ---------------------------------------------------------------------------
// Kernel 3: out = AO(4096x1024 bf16) @ Wout(1024x64) -> fp32 (4096x64).
// Block tile 32(M) x 64(N), 2 waves.
// ---------------------------------------------------------------------------
__global__ __launch_bounds__(128) void out_kernel(
        const short* __restrict__ AO, const float* __restrict__ Wout,
        float* __restrict__ Out) {
    __shared__ short As[32 * 40];
    __shared__ short Bs[64 * 40];
    int m0 = blockIdx.x * 32;
    int t = threadIdx.x, wave = t >> 6, lane = t & 63;
    int quad = lane >> 4, l16 = lane & 15;
    f32x4 acc[4] = {};
    for (int k0 = 0; k0 < 1024; k0 += 32) {
        __syncthreads();
        {   // A tile 32x32 (already bf16)
            int i = t * 8, row = i >> 5, col = i & 31;
            const short* src = AO + (size_t)(m0 + row) * 1024 + k0 + col;
            *(bf16x8*)&As[row * 40 + col] = *(const bf16x8*)src;
        }
        {   // B tile 32x64 fp32 -> bf16, transposed
            int i = t * 16, kr = i >> 6, col = i & 63;
            const float* src = Wout + (k0 + kr) * 64 + col;
#pragma unroll
            for (int j = 0; j < 16; ++j) Bs[(col + j) * 40 + kr] = f2bf(src[j]);
        }
        __syncthreads();
        bf16x8 af = *(const bf16x8*)&As[(wave * 16 + l16) * 40 + quad * 8];
#pragma unroll
        for (int c = 0; c < 4; ++c) {
            bf16x8 bfr = *(const bf16x8*)&Bs[(c * 16 + l16) * 40 + quad * 8];
            acc[c] = __builtin_amdgcn_mfma_f32_16x16x32_bf16(af, bfr, acc[c], 0, 0, 0);
        }
    }
#pragma unroll
    for (int c = 0; c < 4; ++c)
#pragma unroll
        for (int r = 0; r < 4; ++r) {
            int gm = m0 + wave * 16 + quad * 4 + r;
            Out[(gm << 6) + c * 16 + l16] = acc[c][r];
        }
}

// ---------------------------------------------------------------------------
extern "C" void kernel_launch(void* const* d_in, const int* in_sizes, int n_in,
                              void* d_out, int out_size, void* d_ws, size_t ws_size,
                              hipStream_t stream) {
    const float* A    = (const float*)d_in[0];   // (2,2048,256)
    const float* Wqkv = (const float*)d_in[1];   // (256,3072)
    const float* Wout = (const float*)d_in[2];   // (1024,64)
    float* Out = (float*)d_out;                  // (2,2048,64) fp32

    short* ws = (short*)d_ws;
    short* Qb = ws;                  // 2*16*2048*64 = 4194304 elems
    short* Kb = ws + 4194304;
    short* Vb = ws + 8388608;
    short* AO = ws + 12582912;       // 4096*1024 = 4194304 elems

    dim3 g1(64, 48);
    hipLaunchKernelGGL(qkv_kernel, g1, dim3(256), 0, stream, A, Wqkv, Qb, Kb, Vb);
    dim3 g2(32, 32);
    hipLaunchKernelGGL(attn_kernel, g2, dim3(256), 0, stream, Qb, Kb, Vb, AO);
    hipLaunchKernelGGL(out_kernel, dim3(128), dim3(128), 0, stream, AO, Wout, Out);
}